// Round 1
// baseline (675.665 us; speedup 1.0000x reference)
//
#include <hip/hip_runtime.h>

#define IN_FEATURES 4096
#define IN_BLK      1024
#define BLK_R       16
#define NBLOCKS     4
#define ROWS_PER_BLOCK 64
#define CHUNK       32            // floats per row per pipeline step
#define NCH         8             // float4 slots per row per step (CHUNK/4)
#define NITER       (IN_BLK / CHUNK)   // 32

// Each block: 256 threads = 4 waves. Wave w owns diagonal block n=w for 64 rows
// (lane = local row). x staged global->regs->LDS with XOR swizzle; weights go
// through the scalar path (uniform addresses). No barriers: LDS regions are
// wave-private, ordering is same-wave lgkmcnt only.
__global__ __launch_bounds__(256, 2)
void MonarchFactor_kernel(const float* __restrict__ x,
                          const float* __restrict__ w,
                          float* __restrict__ out)
{
    // 4 waves x 2 buffers x (64 rows x 8 float4) x 16B = 64 KiB
    __shared__ float4 lds[NBLOCKS][2][ROWS_PER_BLOCK * NCH];

    const int tid  = threadIdx.x;
    // readfirstlane: force wave-uniformity so weight loads scalarize to s_load
    const int n    = __builtin_amdgcn_readfirstlane(tid >> 6);
    const int lane = tid & 63;
    const long long row0 = (long long)blockIdx.x * ROWS_PER_BLOCK;

    const float* xbase = x + row0 * IN_FEATURES + (long long)n * IN_BLK;
    const float* wbase = w + (long long)n * (BLK_R * IN_BLK);

    float acc[BLK_R];
#pragma unroll
    for (int r = 0; r < BLK_R; ++r) acc[r] = 0.f;

    // staging coords: load-inst g covers rows [8g, 8g+8); lane l -> row 8g + l/8,
    // float4-col l%8. Each 8-lane group reads one aligned 128B line (coalesced).
    const int lrow = lane >> 3;   // 0..7
    const int lcol = lane & 7;    // 0..7
    // LDS slot(r,c) = r*8 + (c ^ (r&7));  (8g+lrow)&7 == lrow
    const int wslot = lrow * NCH + (lcol ^ lrow);     // + g*64
    const float* gld = xbase + (long long)lrow * IN_FEATURES + lcol * 4;

    float4* buf0 = &lds[n][0][0];
    float4* buf1 = &lds[n][1][0];

    float4 G[8];

    // prologue: stage chunk 0 into buf0
#pragma unroll
    for (int g = 0; g < 8; ++g)
        G[g] = *(const float4*)(gld + (long long)(8 * g) * IN_FEATURES);
#pragma unroll
    for (int g = 0; g < 8; ++g)
        buf0[g * 64 + wslot] = G[g];

    for (int t = 0; t < NITER; ++t) {
        float4* cur = (t & 1) ? buf1 : buf0;
        float4* nxt = (t & 1) ? buf0 : buf1;

        // prefetch chunk t+1 into regs (HBM latency hides under the 512 FMAs)
        if (t + 1 < NITER) {
#pragma unroll
            for (int g = 0; g < 8; ++g)
                G[g] = *(const float4*)(gld + (long long)(t + 1) * CHUNK
                                            + (long long)(8 * g) * IN_FEATURES);
        }

        // compute chunk t: 8 swizzled b128 LDS reads, 128 s_load_dwordx4, 512 v_fmac
        const float* wt = wbase + t * CHUNK;
#pragma unroll
        for (int c = 0; c < NCH; ++c) {
            const float4 xv = cur[lane * NCH + (c ^ (lane & 7))];
#pragma unroll
            for (int r = 0; r < BLK_R; ++r) {
                const float4 wv4 = *(const float4*)(wt + r * IN_BLK + c * 4);
                float s = acc[r];
                s = fmaf(xv.x, wv4.x, s);
                s = fmaf(xv.y, wv4.y, s);
                s = fmaf(xv.z, wv4.z, s);
                s = fmaf(xv.w, wv4.w, s);
                acc[r] = s;
            }
        }

        // write chunk t+1 into the other buffer (compiler inserts vmcnt wait)
        if (t + 1 < NITER) {
#pragma unroll
            for (int g = 0; g < 8; ++g)
                nxt[g * 64 + wslot] = G[g];
        }
    }

    // epilogue: 16 outputs for (row0+lane, block n), 4x float4 stores
    float* obase = out + (row0 + lane) * (long long)(NBLOCKS * BLK_R) + n * BLK_R;
#pragma unroll
    for (int j = 0; j < 4; ++j) {
        float4 v = make_float4(acc[4*j+0], acc[4*j+1], acc[4*j+2], acc[4*j+3]);
        *(float4*)(obase + 4 * j) = v;
    }
}

extern "C" void kernel_launch(void* const* d_in, const int* in_sizes, int n_in,
                              void* d_out, int out_size, void* d_ws, size_t ws_size,
                              hipStream_t stream) {
    const float* x = (const float*)d_in[0];
    const float* w = (const float*)d_in[1];
    float* out = (float*)d_out;

    const int rows   = in_sizes[0] / IN_FEATURES;      // 32768
    const int blocks = rows / ROWS_PER_BLOCK;          // 512

    hipLaunchKernelGGL(MonarchFactor_kernel, dim3(blocks), dim3(256), 0, stream,
                       x, w, out);
}